// Round 1
// 717.428 us; speedup vs baseline: 1.0026x; 1.0026x over previous
//
#include <hip/hip_runtime.h>

// ---------------------------------------------------------------------------
// TrajectoryAttention: B=2,S=2048,D=1024,H=16,DH=64,WINDOW=256 (half=128)
// out = ((softmax(QK^T/8 + bias + causal + window)) V) @ W_out
// Window+causal => j in [i-128, i]  (<=129 keys/query): attention is banded.
// All matmuls in bf16 MFMA (16x16x32), fp32 accum. Output fp32.
// R1: reg-staged LDS staging -> global_load_lds width-16 (m97/m151 recipe)
//     in gemm_bt (both instances) and attn_win Q/K staging.
// ---------------------------------------------------------------------------

#define S_ 2048
#define D_ 1024
#define H_ 16
#define D3_ 3072
#define BH_ 2

using bf16x8 = __attribute__((ext_vector_type(8))) short;
using f32x4  = __attribute__((ext_vector_type(4))) float;

__device__ inline f32x4 mfma16(bf16x8 a, bf16x8 b, f32x4 c) {
  return __builtin_amdgcn_mfma_f32_16x16x32_bf16(a, b, c, 0, 0, 0);
}

__device__ inline unsigned short f2bf(float f) {
  unsigned u = __float_as_uint(f);
  u += 0x7fffu + ((u >> 16) & 1u);   // RNE
  return (unsigned short)(u >> 16);
}

// async global->LDS DMA, 16B per lane. LDS dest is wave-uniform base;
// HW writes lane i at dst + i*16B. Global src is per-lane.
__device__ inline void async16(const unsigned short* g, unsigned short* l) {
  __builtin_amdgcn_global_load_lds(
      (const __attribute__((address_space(1))) unsigned int*)g,
      (__attribute__((address_space(3))) unsigned int*)l, 16, 0, 0);
}

// --- fp32 -> bf16 cast, vectorized ----------------------------------------
__global__ __launch_bounds__(256) void cvt_bf16(const float* __restrict__ x,
                                                unsigned short* __restrict__ o, int n4) {
  int idx = blockIdx.x * 256 + threadIdx.x;
  if (idx < n4) {
    float4 v = ((const float4*)x)[idx];
    ushort4 r;
    r.x = f2bf(v.x); r.y = f2bf(v.y); r.z = f2bf(v.z); r.w = f2bf(v.w);
    ((ushort4*)o)[idx] = r;
  }
}

// --- W (K x N fp32, row-major) -> Wt (N x K bf16, row-major) ---------------
__global__ __launch_bounds__(256) void transpose_cvt(const float* __restrict__ W,
                                                     unsigned short* __restrict__ Wt,
                                                     int K, int N) {
  __shared__ float tile[32][33];
  int tx = threadIdx.x, ty = threadIdx.y;
  int n0 = blockIdx.x * 32, k0 = blockIdx.y * 32;
  #pragma unroll
  for (int r = ty; r < 32; r += 8) tile[r][tx] = W[(long)(k0 + r) * N + n0 + tx];
  __syncthreads();
  #pragma unroll
  for (int r = ty; r < 32; r += 8) Wt[(long)(n0 + r) * K + k0 + tx] = f2bf(tile[tx][r]);
}

// --- C[MxN] = A[MxK] * Bt[NxK]^T   (all bf16 in, CT out) -------------------
// 128x128 tile, BK=32, 4 waves, global_load_lds width-16 staging (m97).
template <typename CT>
__global__ __launch_bounds__(256) void gemm_bt(const unsigned short* __restrict__ A,
                                               const unsigned short* __restrict__ Bt,
                                               CT* __restrict__ C, int M, int N, int K) {
  __shared__ unsigned short As[128 * 32];
  __shared__ unsigned short Bs[128 * 32];
  const int tid  = threadIdx.x;
  const int lane = tid & 63;
  const int wave = tid >> 6;
  const int lm   = lane & 15;
  const int quad = lane >> 4;
  const int m0 = blockIdx.y * 128;
  const int n0 = blockIdx.x * 128;
  const int wm = (wave & 1) * 64;
  const int wn = (wave >> 1) * 64;

  // staging geometry: wave w stages rows [w*32, w*32+32) of each tile.
  // one async16 issue (64 lanes x 16B = 1KB) covers 16 rows x 32 bf16 cols:
  //   lane l -> row base+l/4, col (l&3)*8   (matches linear [row][32] LDS)
  const int srow = wave * 32 + (lane >> 2);
  const int scol = (lane & 3) * 8;
  const unsigned short* Ag = A  + (long)(m0 + srow) * K + scol;
  const unsigned short* Bg = Bt + (long)(n0 + srow) * K + scol;
  unsigned short* Al0 = &As[(wave * 32) * 32];
  unsigned short* Al1 = &As[(wave * 32 + 16) * 32];
  unsigned short* Bl0 = &Bs[(wave * 32) * 32];
  unsigned short* Bl1 = &Bs[(wave * 32 + 16) * 32];

  f32x4 zero = {0.f, 0.f, 0.f, 0.f};
  f32x4 acc[4][4];
  #pragma unroll
  for (int i = 0; i < 4; i++)
    #pragma unroll
    for (int j = 0; j < 4; j++) acc[i][j] = zero;

  for (int kk = 0; kk < K; kk += 32) {
    __syncthreads();                       // prior iteration's LDS reads done
    async16(Ag + kk,                Al0);
    async16(Ag + (long)16 * K + kk, Al1);
    async16(Bg + kk,                Bl0);
    async16(Bg + (long)16 * K + kk, Bl1);
    __syncthreads();                       // vmcnt(0) drain -> LDS valid
    bf16x8 af[4], bfr[4];
    #pragma unroll
    for (int mt = 0; mt < 4; mt++)
      af[mt] = *(const bf16x8*)&As[(wm + mt * 16 + lm) * 32 + quad * 8];
    #pragma unroll
    for (int nt = 0; nt < 4; nt++)
      bfr[nt] = *(const bf16x8*)&Bs[(wn + nt * 16 + lm) * 32 + quad * 8];
    #pragma unroll
    for (int mt = 0; mt < 4; mt++)
      #pragma unroll
      for (int nt = 0; nt < 4; nt++)
        acc[mt][nt] = mfma16(af[mt], bfr[nt], acc[mt][nt]);
  }

  #pragma unroll
  for (int mt = 0; mt < 4; mt++)
    #pragma unroll
    for (int r = 0; r < 4; r++) {
      long grow = m0 + wm + mt * 16 + quad * 4 + r;
      #pragma unroll
      for (int nt = 0; nt < 4; nt++) {
        int gcol = n0 + wn + nt * 16 + lm;
        float v = acc[mt][nt][r];
        if constexpr (sizeof(CT) == 2) C[grow * N + gcol] = (CT)f2bf(v);
        else                           C[grow * N + gcol] = (CT)v;
      }
    }
}

// --- windowed attention -----------------------------------------------------
// grid: B*H*(S/64) blocks; block = 256 thr (4 waves, one 16-query m-tile each)
// keys staged: jbase = i0-128 .. i0+63  (192 rows, clamped; masked when j<0)
__global__ __launch_bounds__(256) void attn_win(const unsigned short* __restrict__ qkv,
                                                const float* __restrict__ bias,
                                                unsigned short* __restrict__ attn) {
  __shared__ unsigned short smem[64 * 64 + 192 * 64]; // Qs|Ks, later overlaid by Ps
  __shared__ unsigned short Vt[64 * 200];             // V transposed, padded
  unsigned short* Qs = smem;            // [64][64]
  unsigned short* Ks = smem + 64 * 64;  // [192][64]
  unsigned short* Ps = smem;            // [4][16][200] overlay (12800 <= 16384)

  const int tid  = threadIdx.x;
  const int lane = tid & 63;
  const int wv   = tid >> 6;
  const int lm   = lane & 15;
  const int quad = lane >> 4;

  const int blk = blockIdx.x;
  const int qt = blk & 31;
  const int h  = (blk >> 5) & 15;
  const int b  = blk >> 9;
  const int i0 = qt * 64;
  const int jbase = i0 - 128;

  const long rowbase = (long)b * S_ * D3_;

  { // stage Q via async DMA: wave w stages rows w*16..w*16+15 (two 8-row issues)
    const int qrow = wv * 16 + (lane >> 3);          // rows for issue p=0
    const int qcol = (lane & 7) * 8;
    const unsigned short* qsrc =
        &qkv[rowbase + (long)(i0 + qrow) * D3_ + h * 64 + qcol];
    async16(qsrc,                  &Qs[(wv * 16) * 64]);
    async16(qsrc + (long)8 * D3_,  &Qs[(wv * 16 + 8) * 64]);
  }
  { // stage K via async DMA: wave w stages rows w*48..w*48+47 (six 8-row issues)
    const int kcol = (lane & 7) * 8;
    #pragma unroll
    for (int p = 0; p < 6; p++) {
      int row = wv * 48 + p * 8 + (lane >> 3);
      int j = jbase + row; if (j < 0) j = 0;         // masked later
      const unsigned short* ksrc =
          &qkv[rowbase + (long)j * D3_ + 1024 + h * 64 + kcol];
      async16(ksrc, &Ks[(wv * 48 + p * 8) * 64]);
    }
  }
  if (tid < 192) { // stage V transposed: thread t owns key row jbase+t
    int j = jbase + tid; int jr = j < 0 ? 0 : j;
    const unsigned short* vrow = &qkv[rowbase + (long)jr * D3_ + 2048 + h * 64];
    #pragma unroll
    for (int cc = 0; cc < 8; cc++) {
      uint4 v = *(const uint4*)(vrow + cc * 8);
      const unsigned short* pv = (const unsigned short*)&v;
      #pragma unroll
      for (int q = 0; q < 8; q++) Vt[(cc * 8 + q) * 200 + tid] = pv[q];
    }
  }
  __syncthreads();  // drains DMA (vmcnt) + LDS writes

  // QK^T : 16 queries x 192 keys per wave
  bf16x8 aq[2];
  #pragma unroll
  for (int ks = 0; ks < 2; ks++)
    aq[ks] = *(const bf16x8*)&Qs[(wv * 16 + lm) * 64 + ks * 32 + quad * 8];
  f32x4 zero = {0.f, 0.f, 0.f, 0.f};
  f32x4 sc[12];
  #pragma unroll
  for (int t = 0; t < 12; t++) {
    sc[t] = zero;
    #pragma unroll
    for (int ks = 0; ks < 2; ks++) {
      bf16x8 bk = *(const bf16x8*)&Ks[(t * 16 + lm) * 64 + ks * 32 + quad * 8];
      sc[t] = mfma16(aq[ks], bk, sc[t]);
    }
  }

  // scale + bias + causal/window mask, then softmax over the 192 staged keys
  int irow[4]; float mx[4], lsum[4];
  #pragma unroll
  for (int r = 0; r < 4; r++) { irow[r] = i0 + wv * 16 + quad * 4 + r; mx[r] = -3.0e38f; }
  const long bb = ((long)(b * H_ + h)) * S_;
  #pragma unroll
  for (int t = 0; t < 12; t++) {
    int j = jbase + t * 16 + lm;
    #pragma unroll
    for (int r = 0; r < 4; r++) {
      int i = irow[r];
      float v;
      if (j >= 0 && j <= i && (i - j) <= 128)
        v = sc[t][r] * 0.125f + bias[(bb + i) * S_ + j];
      else
        v = -1e30f;
      sc[t][r] = v;
      mx[r] = fmaxf(mx[r], v);
    }
  }
  #pragma unroll
  for (int off = 8; off >= 1; off >>= 1)
    #pragma unroll
    for (int r = 0; r < 4; r++) mx[r] = fmaxf(mx[r], __shfl_xor(mx[r], off));
  #pragma unroll
  for (int r = 0; r < 4; r++) lsum[r] = 0.f;
  #pragma unroll
  for (int t = 0; t < 12; t++)
    #pragma unroll
    for (int r = 0; r < 4; r++) {
      float p = __expf(sc[t][r] - mx[r]);
      sc[t][r] = p; lsum[r] += p;
    }
  #pragma unroll
  for (int off = 8; off >= 1; off >>= 1)
    #pragma unroll
    for (int r = 0; r < 4; r++) lsum[r] += __shfl_xor(lsum[r], off);

  __syncthreads(); // all waves done with Qs/Ks before Ps overlay write
  #pragma unroll
  for (int t = 0; t < 12; t++)
    #pragma unroll
    for (int r = 0; r < 4; r++)
      Ps[(wv * 16 + quad * 4 + r) * 200 + t * 16 + lm] = f2bf(sc[t][r]);
  __syncthreads();

  // PV : A = P (16x192), B = V (192x64) via Vt rows
  f32x4 oa[4];
  #pragma unroll
  for (int nt = 0; nt < 4; nt++) oa[nt] = zero;
  #pragma unroll
  for (int ks = 0; ks < 6; ks++) {
    bf16x8 ap = *(const bf16x8*)&Ps[(wv * 16 + lm) * 200 + ks * 32 + quad * 8];
    #pragma unroll
    for (int nt = 0; nt < 4; nt++) {
      bf16x8 bv = *(const bf16x8*)&Vt[(nt * 16 + lm) * 200 + ks * 32 + quad * 8];
      oa[nt] = mfma16(ap, bv, oa[nt]);
    }
  }
  #pragma unroll
  for (int nt = 0; nt < 4; nt++)
    #pragma unroll
    for (int r = 0; r < 4; r++) {
      float o = oa[nt][r] / lsum[r];
      attn[((long)b * S_ + irow[r]) * D_ + h * 64 + nt * 16 + lm] = f2bf(o);
    }
}

// ---------------------------------------------------------------------------
extern "C" void kernel_launch(void* const* d_in, const int* in_sizes, int n_in,
                              void* d_out, int out_size, void* d_ws, size_t ws_size,
                              hipStream_t stream) {
  const float* x    = (const float*)d_in[0];
  const float* bias = (const float*)d_in[1];
  // d_in[2] = mask: causal by construction, handled analytically
  const float* Wqkv = (const float*)d_in[3];
  const float* Wout = (const float*)d_in[4];
  float* out = (float*)d_out;

  char* ws = (char*)d_ws;
  unsigned short* xb    = (unsigned short*)(ws);                 //  8.0 MB: 4096x1024 bf16
  unsigned short* Wqkvt = (unsigned short*)(ws + 8388608);       //  6.0 MB: 3072x1024
  unsigned short* Woutt = (unsigned short*)(ws + 14680064);      //  2.0 MB: 1024x1024
  unsigned short* qkv   = (unsigned short*)(ws + 16777216);      // 24.0 MB: 4096x3072
  unsigned short* attn  = (unsigned short*)(ws + 41943040);      //  8.0 MB: 4096x1024

  cvt_bf16<<<4096, 256, 0, stream>>>(x, xb, (BH_ * S_ * D_) / 4);
  transpose_cvt<<<dim3(96, 32), dim3(32, 8), 0, stream>>>(Wqkv, Wqkvt, D_, D3_);
  transpose_cvt<<<dim3(32, 32), dim3(32, 8), 0, stream>>>(Wout, Woutt, D_, D_);

  gemm_bt<unsigned short><<<dim3(24, 32), 256, 0, stream>>>(xb, Wqkvt, qkv,
                                                            BH_ * S_, D3_, D_);
  attn_win<<<BH_ * H_ * (S_ / 64), 256, 0, stream>>>(qkv, bias, attn);
  gemm_bt<float><<<dim3(8, 32), 256, 0, stream>>>(attn, Woutt, out,
                                                  BH_ * S_, D_, D_);
}